// Round 9
// baseline (1517.199 us; speedup 1.0000x reference)
//
#include <hip/hip_runtime.h>
#include <hip/hip_cooperative_groups.h>
#include <math.h>

namespace cg = cooperative_groups;

#define Bk 8
#define Nk 10000
#define Hk 64
#define Lk 4
#define Rk 3
#define Ek 200000
#define FPk 2048

#define C4 (Rk*Ek/4)              /* 150000 edge-quads */
#define CNT4B ((C4 + 255)/256)    /* 586 edge-fill virtual blocks */
#define INITB 2048                /* 8 batches x 256 x0-init virtual blocks */
#define DEGW  (Rk*Nk*16)          /* padded deg: one counter per 64B line */
#define AGGV  30000               /* agg virtual blocks: 4 bpair x 7500 grp */
#define PROJV (157*8)             /* proj virtual blocks */

typedef unsigned short u16;
typedef unsigned int   u32;
typedef _Float16 f16;
typedef __attribute__((ext_vector_type(2))) _Float16 f16x2;
typedef __attribute__((ext_vector_type(8))) _Float16 f16x8;
typedef __attribute__((ext_vector_type(4))) float f32x4;

__device__ __forceinline__ f16x2 as_h2(u32 u){
    union{u32 i; f16x2 h;} v; v.i = u; return v.h;
}
__device__ __forceinline__ u16 f2h_bits(float f){
    union{f16 h; u16 u;} v; v.h = (f16)f; return v.u;
}

// ---------------------------------------------------------------------------
// k_all: the whole net as ONE cooperative persistent kernel.
// Phases (grid-stride loops over the old virtual-block spaces, bodies
// byte-identical to the R5/R8-proven kernels), separated by grid.sync():
//   P0  prep: wt layout + padded-deg zero (v<256) | FiLM-1 (v 256..767)
//   P1  efill (v<CNT4B) | x0-init+FiLM-2 (after)
//   4x { agg (30000 virt) ; sync ; proj+LN+ReLU[+readout] (1256 virt) ; sync }
// Rationale: R8 accounting shows ~85us of inter-dispatch overhead across 10
// boundaries (~9us each, matches known ~10us launch cost); phases are at
// their measured floors (agg: L2 line-rate, R0/R2/R3/R7-invariant).
// __launch_bounds__(256,6) -> guaranteed 6 blocks/CU -> G=1536 = 6144
// co-resident agg waves >= the ~5500 effective of the 30000-block dispatch
// (R1 lesson: never shrink agg TLP). G%8==0 keeps v&3/v&7 XCD pinning.
// proj reads wt from L2 (no 32KB LDS stage -> occupancy stays 6/CU).
// ---------------------------------------------------------------------------
__global__ __launch_bounds__(256, 6) void k_all(
        const float* __restrict__ ctl, const float* __restrict__ dt,
        const float* __restrict__ drug_fp, const float* __restrict__ edge_w,
        const int* __restrict__ cell_idx, const int* __restrict__ edge_index,
        const float* __restrict__ W_se, const float* __restrict__ b_se,
        const float* __restrict__ cell_emb,
        const float* __restrict__ W_f1, const float* __restrict__ b_f1,
        const float* __restrict__ W_f2, const float* __restrict__ b_f2,
        const float* __restrict__ Wself, const float* __restrict__ Wrel,
        const float* __restrict__ ln_g, const float* __restrict__ ln_b,
        const float* __restrict__ W_out, const float* __restrict__ b_out,
        float* __restrict__ out,
        int* __restrict__ deg, u32* __restrict__ epack,
        float* __restrict__ hid, u16* __restrict__ xh,
        u16* __restrict__ aggh, u16* __restrict__ wt){
    cg::grid_group grid = cg::this_grid();
    const int G   = gridDim.x;
    const int tid = threadIdx.x;
    __shared__ float red[256];
    __shared__ float g1l[64], btl[64];
    __shared__ int2  stash[4][64];

    // ================= P0: weight prep + deg zero | FiLM-1 =================
    for(int v = blockIdx.x; v < 768; v += G){
        if(v < 256){
            int idx = v*256 + tid;                   // 0..65535
            if(idx < DEGW/8){
                *(int4*)&deg[idx*8]     = make_int4(0,0,0,0);
                *(int4*)&deg[idx*8 + 4] = make_int4(0,0,0,0);
            }
            int j    = idx & 7;
            int lane = (idx >> 3) & 63;
            int jt   = (idx >> 9) & 3;
            int kc   = (idx >> 11) & 1;
            int mt   = (idx >> 12) & 3;
            int l    = idx >> 14;
            int k    = kc*32 + (lane >> 4)*8 + j;
            int col  = jt*16 + (lane & 15);
            float w = (mt == 0) ? Wself[(l*64 + k)*64 + col]
                                : Wrel[((l*3 + (mt-1))*64 + k)*64 + col];
            wt[idx] = f2h_bits(w);
        }else{
            int bb = v - 256;                        // 0..511
            int b = bb >> 6, h = bb & 63;
            const float* fpb = drug_fp + b*FPk;
            float acc = 0.f;
            for(int k = tid; k < FPk; k += 256)
                acc += fpb[k] * W_f1[k*64 + h];
            __syncthreads();
            red[tid] = acc;
            __syncthreads();
            for(int s = 128; s >= 1; s >>= 1){
                if(tid < s) red[tid] += red[tid + s];
                __syncthreads();
            }
            if(tid == 0) hid[b*64 + h] = fmaxf(red[0] + b_f1[h], 0.f);
        }
    }
    grid.sync();

    // ================= P1: ELL edge fill | x0 init =================
    for(int v = blockIdx.x; v < CNT4B + INITB; v += G){
        if(v < CNT4B){
            int idx = v*256 + tid;
            if(idx < C4){
                int g = idx*4;
                int r = g / Ek, e = g % Ek;          // Ek%4==0 -> quad shares r
                int4   s4 = *(const int4*)  &edge_index[r*2*Ek + e];
                int4   d4 = *(const int4*)  &edge_index[r*2*Ek + Ek + e];
                float4 w4 = *(const float4*)&edge_w   [r*Ek + e];
                int* dg = deg + (size_t)r*Nk*16;
                size_t ebase = (size_t)r*Nk;
                int pos;
                pos = atomicAdd(&dg[(size_t)d4.x*16], 1);
                if(pos < 64) epack[((ebase + d4.x) << 6) + pos] = ((u32)f2h_bits(w4.x) << 16) | (u32)s4.x;
                pos = atomicAdd(&dg[(size_t)d4.y*16], 1);
                if(pos < 64) epack[((ebase + d4.y) << 6) + pos] = ((u32)f2h_bits(w4.y) << 16) | (u32)s4.y;
                pos = atomicAdd(&dg[(size_t)d4.z*16], 1);
                if(pos < 64) epack[((ebase + d4.z) << 6) + pos] = ((u32)f2h_bits(w4.z) << 16) | (u32)s4.z;
                pos = atomicAdd(&dg[(size_t)d4.w*16], 1);
                if(pos < 64) epack[((ebase + d4.w) << 6) + pos] = ((u32)f2h_bits(w4.w) << 16) | (u32)s4.w;
            }
        }else{
            int vb  = v - CNT4B;                     // 0..2047
            int b   = vb >> 8;
            int blk = vb & 255;
            __syncthreads();
            if(tid < 128){
                float acc = b_f2[tid];
                #pragma unroll 8
                for(int k = 0; k < 64; ++k)
                    acc += hid[b*64 + k] * W_f2[k*128 + tid];
                if(tid < 64) g1l[tid] = 1.f + tanhf(acc);
                else         btl[tid - 64] = acc;
            }
            __syncthreads();
            int ci = cell_idx[b];
            const int per_b = Nk*8;                  // 80000 feat-octets
            for(int o = blk*256 + tid; o < per_b; o += 256*256){
                int hq = o & 7;
                int n  = o >> 3;
                float c = ctl[b*Nk + n], d = dt[b*Nk + n];
                u32 pk[4];
                #pragma unroll
                for(int j = 0; j < 8; j += 2){
                    int h0 = hq*8 + j, h1 = h0 + 1;
                    float w0 = W_se[h0], s0 = b_se[h0];
                    float w1 = W_se[h1], s1 = b_se[h1];
                    float v0 = fmaxf(c*w0 + s0, 0.f) + fmaxf(d*w0 + s0, 0.f)
                             + cell_emb[ci*64 + h0];
                    float v1 = fmaxf(c*w1 + s1, 0.f) + fmaxf(d*w1 + s1, 0.f)
                             + cell_emb[ci*64 + h1];
                    v0 = v0 * g1l[h0] + btl[h0];
                    v1 = v1 * g1l[h1] + btl[h1];
                    pk[j >> 1] = (u32)f2h_bits(v0) | ((u32)f2h_bits(v1) << 16);
                }
                *(int4*)&xh[(((size_t)b*Nk + n)*64) + hq*8] = make_int4(pk[0], pk[1], pk[2], pk[3]);
            }
        }
    }
    grid.sync();

    // ================= layers =================
    for(int l = 0; l < Lk; ++l){
        // ---- agg phase (R5-proven body; v&3 const per block since G%4==0) ----
        for(int v = blockIdx.x; v < AGGV; v += G){
            int bpair = v & 3;
            int grp   = v >> 2;
            int wq    = tid >> 6;
            int wid   = grp*4 + wq;                  // (r,dst)
            int lane  = tid & 63;
            int fg    = lane & 31;
            int bl    = lane >> 5;
            int b     = bpair*2 + bl;
            int r = wid / Nk, dst = wid % Nk;
            int cnt = deg[(size_t)wid*16]; if(cnt > 64) cnt = 64;
            const u32* ep = epack + ((size_t)wid << 6);
            const char* xb = (const char*)xh + (size_t)b*Nk*128 + fg*4;

            f16x2 A = (f16x2){0,0}, C = (f16x2){0,0};
            int2* st = stash[wq];
            if(lane < cnt){
                u32 e = ep[lane];
                st[lane] = make_int2((int)((e & 0xFFFFu) << 7),
                                     (int)((e >> 16) | (e & 0xFFFF0000u)));
            }
            int t = 0;
            for(; t + 8 <= cnt; t += 8){
                int4 q01 = *(const int4*)&st[t];
                int4 q23 = *(const int4*)&st[t+2];
                int4 q45 = *(const int4*)&st[t+4];
                int4 q67 = *(const int4*)&st[t+6];
                u32 u0 = *(const u32*)(xb + q01.x);
                u32 u1 = *(const u32*)(xb + q01.z);
                u32 u2 = *(const u32*)(xb + q23.x);
                u32 u3 = *(const u32*)(xb + q23.z);
                u32 u4 = *(const u32*)(xb + q45.x);
                u32 u5 = *(const u32*)(xb + q45.z);
                u32 u6 = *(const u32*)(xb + q67.x);
                u32 u7 = *(const u32*)(xb + q67.z);
                A += as_h2(u0)*as_h2(q01.y); C += as_h2(u1)*as_h2(q01.w);
                A += as_h2(u2)*as_h2(q23.y); C += as_h2(u3)*as_h2(q23.w);
                A += as_h2(u4)*as_h2(q45.y); C += as_h2(u5)*as_h2(q45.w);
                A += as_h2(u6)*as_h2(q67.y); C += as_h2(u7)*as_h2(q67.w);
            }
            for(; t + 2 <= cnt; t += 2){
                int4 q01 = *(const int4*)&st[t];
                u32 u0 = *(const u32*)(xb + q01.x);
                u32 u1 = *(const u32*)(xb + q01.z);
                A += as_h2(u0)*as_h2(q01.y); C += as_h2(u1)*as_h2(q01.w);
            }
            if(t < cnt){
                int2 pq = st[t];
                u32 u = *(const u32*)(xb + pq.x);
                A += as_h2(u)*as_h2(pq.y);
            }
            float a0 = (float)A.x + (float)C.x;
            float a1 = (float)A.y + (float)C.y;
            u32 packed = (u32)f2h_bits(a0) | ((u32)f2h_bits(a1) << 16);
            ((u32*)aggh)[(((size_t)r*Bk + b)*Nk + dst)*32 + fg] = packed;
        }
        grid.sync();

        // ---- proj phase (R8 geometry, wt from L2; v&7 const since G%8==0) ----
        int last = (l == Lk-1);
        const u16* wl = wt + (size_t)l*16384;
        for(int v = blockIdx.x; v < PROJV; v += G){
            int lane = tid & 63;
            int wq   = tid >> 6;
            int k8   = v & 7;
            int b    = ((k8 & 3) << 1) | (k8 >> 2);
            int tile = v >> 3;                       // 0..156
            int n0   = tile*64 + wq*16;
            int mrow = lane & 15;
            int kq   = lane >> 4;
            int nA = n0 + mrow; if(nA >= Nk) nA = Nk - 1;

            f32x4 acc[4];
            #pragma unroll
            for(int jt = 0; jt < 4; ++jt) acc[jt] = (f32x4){0.f,0.f,0.f,0.f};

            #pragma unroll
            for(int mt = 0; mt < 4; ++mt){
                const u16* arowA = ((mt == 0)
                    ? xh   + (size_t)b*Nk*64
                    : aggh + (((size_t)(mt-1)*Bk + b)*Nk)*64) + (size_t)nA*64;
                #pragma unroll
                for(int kc = 0; kc < 2; ++kc){
                    f16x8 aA = *(const f16x8*)(arowA + kc*32 + kq*8);
                    #pragma unroll
                    for(int jt = 0; jt < 4; ++jt){
                        f16x8 bfrag = *(const f16x8*)(wl + ((size_t)((mt*2 + kc)*4 + jt)*64 + lane)*8);
                        acc[jt] = __builtin_amdgcn_mfma_f32_16x16x32_f16(aA, bfrag, acc[jt], 0, 0, 0);
                    }
                }
            }

            float gv[4], bv[4], wo[4];
            #pragma unroll
            for(int jt = 0; jt < 4; ++jt){
                int f = jt*16 + mrow;
                gv[jt] = ln_g[l*64 + f];
                bv[jt] = ln_b[l*64 + f];
                wo[jt] = W_out[f];
            }
            float bo = b_out[0];
            u16* xdst = xh + (size_t)b*Nk*64;

            #pragma unroll
            for(int vv = 0; vv < 4; ++vv){
                float s1 = acc[0][vv] + acc[1][vv] + acc[2][vv] + acc[3][vv];
                float s2 = acc[0][vv]*acc[0][vv] + acc[1][vv]*acc[1][vv]
                         + acc[2][vv]*acc[2][vv] + acc[3][vv]*acc[3][vv];
                #pragma unroll
                for(int off = 1; off <= 8; off <<= 1){
                    s1 += __shfl_xor(s1, off);
                    s2 += __shfl_xor(s2, off);
                }
                float mu  = s1 * 0.015625f;
                float var = s2 * 0.015625f - mu*mu;
                float rstd = rsqrtf(var + 1e-3f);
                int node = n0 + kq*4 + vv;
                if(!last){
                    if(node < Nk){
                        #pragma unroll
                        for(int jt = 0; jt < 4; ++jt){
                            float o = (acc[jt][vv] - mu) * rstd * gv[jt] + bv[jt];
                            xdst[(size_t)node*64 + jt*16 + mrow] = f2h_bits(fmaxf(o, 0.f));
                        }
                    }
                }else{
                    float s3 = 0.f;
                    #pragma unroll
                    for(int jt = 0; jt < 4; ++jt){
                        float o = (acc[jt][vv] - mu) * rstd * gv[jt] + bv[jt];
                        s3 += fmaxf(o, 0.f) * wo[jt];
                    }
                    #pragma unroll
                    for(int off = 1; off <= 8; off <<= 1)
                        s3 += __shfl_xor(s3, off);
                    if(mrow == 0 && node < Nk)
                        out[(size_t)b*Nk + node] = s3 + bo;
                }
            }
        }
        if(l < Lk-1) grid.sync();
    }
}

// ---------------------------------------------------------------------------
extern "C" void kernel_launch(void* const* d_in, const int* in_sizes, int n_in,
                              void* d_out, int out_size, void* d_ws, size_t ws_size,
                              hipStream_t stream){
    const float* ctl        = (const float*)d_in[0];
    const float* dt         = (const float*)d_in[1];
    const float* drug_fp    = (const float*)d_in[2];
    const float* edge_w     = (const float*)d_in[3];
    const int*   cell_idx   = (const int*)  d_in[4];
    const int*   edge_index = (const int*)  d_in[5];
    const float* W_se       = (const float*)d_in[6];
    const float* b_se       = (const float*)d_in[7];
    const float* cell_emb   = (const float*)d_in[8];
    const float* W_f1       = (const float*)d_in[9];
    const float* b_f1       = (const float*)d_in[10];
    const float* W_f2       = (const float*)d_in[11];
    const float* b_f2       = (const float*)d_in[12];
    const float* Wself      = (const float*)d_in[13];
    const float* Wrel       = (const float*)d_in[14];
    const float* ln_g       = (const float*)d_in[15];
    const float* ln_b       = (const float*)d_in[16];
    const float* W_out      = (const float*)d_in[17];
    const float* b_out      = (const float*)d_in[18];
    float* out = (float*)d_out;

    char* p = (char*)d_ws;
    auto alloc = [&](size_t bytes)->char*{
        char* r = p; p += (bytes + 255) & ~(size_t)255; return r;
    };
    int*   deg    = (int*)  alloc((size_t)DEGW*4);       /* padded, 1.92MB */
    u32*   epack  = (u32*)  alloc((size_t)Rk*Nk*64*4);   /* ELL 4B, 7.68MB */
    float* hid    = (float*)alloc((size_t)Bk*64*4);
    u16*   xh     = (u16*)  alloc((size_t)Bk*Nk*64*2);
    u16*   aggh   = (u16*)  alloc((size_t)3*Bk*Nk*64*2);
    u16*   wt     = (u16*)  alloc((size_t)Lk*16384*2);

    // grid = guaranteed-co-resident blocks (clamped by runtime occupancy).
    int occ = 0;
    hipOccupancyMaxActiveBlocksPerMultiprocessor(&occ, (const void*)k_all, 256, 0);
    if(occ < 1) occ = 1;
    if(occ > 6) occ = 6;
    int G = occ * 256;                         // 256 CUs; G%8==0 always

    void* args[] = {
        (void*)&ctl, (void*)&dt, (void*)&drug_fp, (void*)&edge_w,
        (void*)&cell_idx, (void*)&edge_index, (void*)&W_se, (void*)&b_se,
        (void*)&cell_emb, (void*)&W_f1, (void*)&b_f1, (void*)&W_f2,
        (void*)&b_f2, (void*)&Wself, (void*)&Wrel, (void*)&ln_g,
        (void*)&ln_b, (void*)&W_out, (void*)&b_out, (void*)&out,
        (void*)&deg, (void*)&epack, (void*)&hid, (void*)&xh,
        (void*)&aggh, (void*)&wt
    };
    hipLaunchCooperativeKernel((const void*)k_all, dim3(G), dim3(256),
                               args, 0, stream);
}

// Round 10
// 356.129 us; speedup vs baseline: 4.2603x; 4.2603x over previous
//
#include <hip/hip_runtime.h>
#include <hip/hip_bf16.h>
#include <math.h>

#define Bk 8
#define Nk 10000
#define Hk 64
#define Lk 4
#define Rk 3
#define Ek 200000
#define FPk 2048

#define C4 (Rk*Ek/4)              /* 150000 edge-quads */
#define EFB ((C4 + 255)/256)      /* 586 per-XCD edge-scan block groups */
#define INITB 2048                /* 8 batches x 256 x0-init blocks */
#define DEGW  (Rk*Nk*16)          /* padded deg: one counter per 64B line */
#define NPART 1250                /* dst nodes per XCD partition */

typedef unsigned short u16;
typedef unsigned int   u32;
typedef _Float16 f16;
typedef __attribute__((ext_vector_type(2))) _Float16 f16x2;
typedef __attribute__((ext_vector_type(8))) _Float16 f16x8;
typedef __attribute__((ext_vector_type(4))) float f32x4;

__device__ __forceinline__ f16x2 as_h2(u32 u){
    union{u32 i; f16x2 h;} v; v.i = u; return v.h;
}
__device__ __forceinline__ u16 f2h_bits(float f){
    union{f16 h; u16 u;} v; v.h = (f16)f; return v.u;
}

// ---------------------------------------------------------------------------
// k_prep0: weight prep (fp16, MFMA B layout) + padded-deg zeroing
//          (blocks 0..255) + FiLM stage 1 (blocks 256..767).  [R5-proven]
// ---------------------------------------------------------------------------
__global__ void k_prep0(const float* __restrict__ Wself, const float* __restrict__ Wrel,
                        u16* __restrict__ wt, int* __restrict__ deg,
                        const float* __restrict__ fp, const float* __restrict__ W1,
                        const float* __restrict__ b1, float* __restrict__ hid){
    __shared__ float red[256];
    if(blockIdx.x < 256){
        int idx = blockIdx.x*256 + threadIdx.x;      // 0..65535
        if(idx < DEGW/8){                            // zero 8 ints each (60000 thr)
            *(int4*)&deg[idx*8]     = make_int4(0,0,0,0);
            *(int4*)&deg[idx*8 + 4] = make_int4(0,0,0,0);
        }
        int j    = idx & 7;
        int lane = (idx >> 3) & 63;
        int jt   = (idx >> 9) & 3;
        int kc   = (idx >> 11) & 1;
        int mt   = (idx >> 12) & 3;
        int l    = idx >> 14;
        int k    = kc*32 + (lane >> 4)*8 + j;
        int col  = jt*16 + (lane & 15);
        float w = (mt == 0) ? Wself[(l*64 + k)*64 + col]
                            : Wrel[((l*3 + (mt-1))*64 + k)*64 + col];
        wt[idx] = f2h_bits(w);
    }else{
        int bb = blockIdx.x - 256;                   // 0..511
        int b = bb >> 6, h = bb & 63;
        const float* fpb = fp + b*FPk;
        float acc = 0.f;
        for(int k = threadIdx.x; k < FPk; k += 256)
            acc += fpb[k] * W1[k*64 + h];
        red[threadIdx.x] = acc;
        __syncthreads();
        for(int s = 128; s >= 1; s >>= 1){
            if(threadIdx.x < s) red[threadIdx.x] += red[threadIdx.x + s];
            __syncthreads();
        }
        if(threadIdx.x == 0) hid[b*64 + h] = fmaxf(red[0] + b1[h], 0.f);
    }
}

// ---------------------------------------------------------------------------
// k_efx: XCD-partitioned ELL edge fill + x0 init, one dispatch.
//  - Blocks < 8*EFB: edge fill. XCD = blockIdx&7 (empirical %8 round-robin)
//    scans ALL edge quads (quad id = blockIdx>>3 block group) but processes
//    only edges with dst/NPART == its partition. Every deg-counter line and
//    epack line is then RMW'd/written by EXACTLY ONE XCD -> atomics become
//    XCD-L2-local, zero cross-XCD line migration (probe of the R4/R5 atomic
//    model; if atomics execute at the MALL instead, this is neutral).
//    Read amplification 8x (7.2->57.6MB) is L3-served, ~3-5us.
//  - Blocks after: x0 init (one batch per 256-block group, FiLM-2 in LDS).
// ---------------------------------------------------------------------------
__global__ void k_efx(const int* __restrict__ edge_index, const float* __restrict__ edge_weight,
                      int* __restrict__ deg, u32* __restrict__ epack,
                      const float* __restrict__ ctl, const float* __restrict__ dt,
                      const int* __restrict__ cell_idx,
                      const float* __restrict__ W_se, const float* __restrict__ b_se,
                      const float* __restrict__ cell_emb,
                      const float* __restrict__ hid, const float* __restrict__ W2,
                      const float* __restrict__ b2,
                      u16* __restrict__ xh){
    __shared__ float g1l[64], btl[64];
    if(blockIdx.x < 8*EFB){
        int part = blockIdx.x & 7;                  // XCD partition (dst range)
        int idx  = (blockIdx.x >> 3)*256 + threadIdx.x;
        if(idx >= C4) return;
        int g = idx*4;
        int r = g / Ek, e = g % Ek;                 // Ek%4==0 -> quad shares r
        int4   d4 = *(const int4*)  &edge_index [r*2*Ek + Ek + e];
        int lo = part*NPART, hi = lo + NPART;
        // quick reject: most quads have no edge in this partition
        if((d4.x < lo || d4.x >= hi) && (d4.y < lo || d4.y >= hi) &&
           (d4.z < lo || d4.z >= hi) && (d4.w < lo || d4.w >= hi)) return;
        int4   s4 = *(const int4*)  &edge_index [r*2*Ek + e];
        float4 w4 = *(const float4*)&edge_weight[r*Ek + e];
        int* dg = deg + (size_t)r*Nk*16;
        size_t ebase = (size_t)r*Nk;
        int pos;
        if(d4.x >= lo && d4.x < hi){
            pos = atomicAdd(&dg[(size_t)d4.x*16], 1);
            if(pos < 64) epack[((ebase + d4.x) << 6) + pos] = ((u32)f2h_bits(w4.x) << 16) | (u32)s4.x;
        }
        if(d4.y >= lo && d4.y < hi){
            pos = atomicAdd(&dg[(size_t)d4.y*16], 1);
            if(pos < 64) epack[((ebase + d4.y) << 6) + pos] = ((u32)f2h_bits(w4.y) << 16) | (u32)s4.y;
        }
        if(d4.z >= lo && d4.z < hi){
            pos = atomicAdd(&dg[(size_t)d4.z*16], 1);
            if(pos < 64) epack[((ebase + d4.z) << 6) + pos] = ((u32)f2h_bits(w4.z) << 16) | (u32)s4.z;
        }
        if(d4.w >= lo && d4.w < hi){
            pos = atomicAdd(&dg[(size_t)d4.w*16], 1);
            if(pos < 64) epack[((ebase + d4.w) << 6) + pos] = ((u32)f2h_bits(w4.w) << 16) | (u32)s4.w;
        }
    }else{
        int vb  = blockIdx.x - 8*EFB;               // 0..2047
        int b   = vb >> 8;                          // batch
        int blk = vb & 255;
        int t = threadIdx.x;
        if(t < 128){
            float acc = b2[t];
            #pragma unroll 8
            for(int k = 0; k < 64; ++k)
                acc += hid[b*64 + k] * W2[k*128 + t];
            if(t < 64) g1l[t] = 1.f + tanhf(acc);
            else       btl[t - 64] = acc;
        }
        __syncthreads();
        int ci = cell_idx[b];
        const int per_b = Nk*8;                     // 80000 feat-octets
        for(int o = blk*256 + t; o < per_b; o += 256*256){
            int hq = o & 7;
            int n  = o >> 3;
            float c = ctl[b*Nk + n], d = dt[b*Nk + n];
            u32 pk[4];
            #pragma unroll
            for(int j = 0; j < 8; j += 2){
                int h0 = hq*8 + j, h1 = h0 + 1;
                float w0 = W_se[h0], s0 = b_se[h0];
                float w1 = W_se[h1], s1 = b_se[h1];
                float v0 = fmaxf(c*w0 + s0, 0.f) + fmaxf(d*w0 + s0, 0.f)
                         + cell_emb[ci*64 + h0];
                float v1 = fmaxf(c*w1 + s1, 0.f) + fmaxf(d*w1 + s1, 0.f)
                         + cell_emb[ci*64 + h1];
                v0 = v0 * g1l[h0] + btl[h0];
                v1 = v1 * g1l[h1] + btl[h1];
                pk[j >> 1] = (u32)f2h_bits(v0) | ((u32)f2h_bits(v1) << 16);
            }
            *(int4*)&xh[(((size_t)b*Nk + n)*64) + hq*8] = make_int4(pk[0], pk[1], pk[2], pk[3]);
        }
    }
}

// ---------------------------------------------------------------------------
// agg (fp16): R0-proven hot loop, ELL addressing, 4B entries unpacked ONCE at
// stash fill. wave = one (r,dst) x 2 batches x 32 feat-dwords.
// bpair=blockIdx&3 -> per-XCD 2.56MB x-slice (L2-hit). At the measured L2
// line-rate floor (~13 TB/s; R0/R2/R3-invariant; fp8 blocked by accuracy R7;
// grid.sync fusion blocked by coherence-traffic blowup R9).
// ---------------------------------------------------------------------------
__global__ __launch_bounds__(256) void k_agg(const u16* __restrict__ xh,
                      const int* __restrict__ deg, const u32* __restrict__ epack,
                      u16* __restrict__ aggh){
    __shared__ int2 stash[4][64];
    int bpair = blockIdx.x & 3;
    int grp   = blockIdx.x >> 2;                   // 0..7499
    int wq    = threadIdx.x >> 6;
    int wid   = grp*4 + wq;                        // 0..29999 = (r,dst)
    int lane  = threadIdx.x & 63;
    int fg    = lane & 31;                         // feat dword: feats fg*2, fg*2+1
    int bl    = lane >> 5;                         // local batch 0/1
    int b     = bpair*2 + bl;
    int r = wid / Nk, dst = wid % Nk;
    int cnt = deg[(size_t)wid*16]; if(cnt > 64) cnt = 64;
    const u32* ep = epack + ((size_t)wid << 6);
    const char* xb = (const char*)xh + (size_t)b*Nk*128 + fg*4;

    f16x2 A = (f16x2){0,0}, C = (f16x2){0,0};      // 2 accumulation chains
    int2* st = stash[wq];
    if(lane < cnt){
        u32 e = ep[lane];
        st[lane] = make_int2((int)((e & 0xFFFFu) << 7),
                             (int)((e >> 16) | (e & 0xFFFF0000u)));
    }
    int t = 0;
    for(; t + 8 <= cnt; t += 8){
        int4 q01 = *(const int4*)&st[t];
        int4 q23 = *(const int4*)&st[t+2];
        int4 q45 = *(const int4*)&st[t+4];
        int4 q67 = *(const int4*)&st[t+6];
        u32 u0 = *(const u32*)(xb + q01.x);
        u32 u1 = *(const u32*)(xb + q01.z);
        u32 u2 = *(const u32*)(xb + q23.x);
        u32 u3 = *(const u32*)(xb + q23.z);
        u32 u4 = *(const u32*)(xb + q45.x);
        u32 u5 = *(const u32*)(xb + q45.z);
        u32 u6 = *(const u32*)(xb + q67.x);
        u32 u7 = *(const u32*)(xb + q67.z);
        A += as_h2(u0)*as_h2(q01.y); C += as_h2(u1)*as_h2(q01.w);
        A += as_h2(u2)*as_h2(q23.y); C += as_h2(u3)*as_h2(q23.w);
        A += as_h2(u4)*as_h2(q45.y); C += as_h2(u5)*as_h2(q45.w);
        A += as_h2(u6)*as_h2(q67.y); C += as_h2(u7)*as_h2(q67.w);
    }
    for(; t + 2 <= cnt; t += 2){
        int4 q01 = *(const int4*)&st[t];
        u32 u0 = *(const u32*)(xb + q01.x);
        u32 u1 = *(const u32*)(xb + q01.z);
        A += as_h2(u0)*as_h2(q01.y); C += as_h2(u1)*as_h2(q01.w);
    }
    if(t < cnt){
        int2 p = st[t];
        u32 u = *(const u32*)(xb + p.x);
        A += as_h2(u)*as_h2(p.y);
    }
    float a0 = (float)A.x + (float)C.x;
    float a1 = (float)A.y + (float)C.y;
    u32 packed = (u32)f2h_bits(a0) | ((u32)f2h_bits(a1) << 16);
    ((u32*)aggh)[(((size_t)r*Bk + b)*Nk + dst)*32 + fg] = packed;
}

// ---------------------------------------------------------------------------
// MFMA projection (fp16) + LN + ReLU (+ fused readout on last layer).
// wt staged in LDS; 64 nodes/block (16/wave), 1256 blocks.  [R8]
// ---------------------------------------------------------------------------
__global__ __launch_bounds__(256) void k_proj_mfma(u16* __restrict__ xh,
        const u16* __restrict__ aggh, const u16* __restrict__ wt,
        const float* __restrict__ ln_g, const float* __restrict__ ln_b, int l,
        int last, const float* __restrict__ W_out, const float* __restrict__ b_out,
        float* __restrict__ out){
    __shared__ u16 wls[16384];
    const u16* wl = wt + (size_t)l*16384;
    for(int i = threadIdx.x; i < 2048; i += 256)
        *(int4*)&wls[i*8] = *(const int4*)&wl[i*8];
    __syncthreads();

    int lane = threadIdx.x & 63;
    int wq   = threadIdx.x >> 6;
    int k8   = blockIdx.x & 7;
    int b    = ((k8 & 3) << 1) | (k8 >> 2);   // inverse of xcd(b)=(b>>1)+4*(b&1)
    int tile = blockIdx.x >> 3;
    int n0   = tile*64 + wq*16;               // 16 nodes for this wave
    int mrow = lane & 15;
    int kq   = lane >> 4;
    int nA = n0 + mrow; if(nA >= Nk) nA = Nk - 1;

    f32x4 acc[4];
    #pragma unroll
    for(int jt = 0; jt < 4; ++jt) acc[jt] = (f32x4){0.f,0.f,0.f,0.f};

    #pragma unroll
    for(int mt = 0; mt < 4; ++mt){
        const u16* arowA = ((mt == 0)
            ? xh   + (size_t)b*Nk*64
            : aggh + (((size_t)(mt-1)*Bk + b)*Nk)*64) + (size_t)nA*64;
        #pragma unroll
        for(int kc = 0; kc < 2; ++kc){
            f16x8 aA = *(const f16x8*)(arowA + kc*32 + kq*8);
            #pragma unroll
            for(int jt = 0; jt < 4; ++jt){
                f16x8 bfrag = *(const f16x8*)(wls + ((size_t)((mt*2 + kc)*4 + jt)*64 + lane)*8);
                acc[jt] = __builtin_amdgcn_mfma_f32_16x16x32_f16(aA, bfrag, acc[jt], 0, 0, 0);
            }
        }
    }

    float gv[4], bv[4], wo[4];
    #pragma unroll
    for(int jt = 0; jt < 4; ++jt){
        int f = jt*16 + mrow;
        gv[jt] = ln_g[l*64 + f];
        bv[jt] = ln_b[l*64 + f];
        wo[jt] = W_out[f];
    }
    float bo = b_out[0];
    u16* xdst = xh + (size_t)b*Nk*64;

    #pragma unroll
    for(int v = 0; v < 4; ++v){
        float s1 = acc[0][v] + acc[1][v] + acc[2][v] + acc[3][v];
        float s2 = acc[0][v]*acc[0][v] + acc[1][v]*acc[1][v]
                 + acc[2][v]*acc[2][v] + acc[3][v]*acc[3][v];
        #pragma unroll
        for(int off = 1; off <= 8; off <<= 1){
            s1 += __shfl_xor(s1, off);
            s2 += __shfl_xor(s2, off);
        }
        float mu  = s1 * 0.015625f;
        float var = s2 * 0.015625f - mu*mu;
        float rstd = rsqrtf(var + 1e-3f);
        int node = n0 + kq*4 + v;
        if(!last){
            if(node < Nk){
                #pragma unroll
                for(int jt = 0; jt < 4; ++jt){
                    float o = (acc[jt][v] - mu) * rstd * gv[jt] + bv[jt];
                    xdst[(size_t)node*64 + jt*16 + mrow] = f2h_bits(fmaxf(o, 0.f));
                }
            }
        }else{
            float s3 = 0.f;
            #pragma unroll
            for(int jt = 0; jt < 4; ++jt){
                float o = (acc[jt][v] - mu) * rstd * gv[jt] + bv[jt];
                s3 += fmaxf(o, 0.f) * wo[jt];
            }
            #pragma unroll
            for(int off = 1; off <= 8; off <<= 1)
                s3 += __shfl_xor(s3, off);
            if(mrow == 0 && node < Nk)
                out[(size_t)b*Nk + node] = s3 + bo;
        }
    }
}

// ---------------------------------------------------------------------------
extern "C" void kernel_launch(void* const* d_in, const int* in_sizes, int n_in,
                              void* d_out, int out_size, void* d_ws, size_t ws_size,
                              hipStream_t stream){
    const float* ctl        = (const float*)d_in[0];
    const float* dt         = (const float*)d_in[1];
    const float* drug_fp    = (const float*)d_in[2];
    const float* edge_w     = (const float*)d_in[3];
    const int*   cell_idx   = (const int*)  d_in[4];
    const int*   edge_index = (const int*)  d_in[5];
    const float* W_se       = (const float*)d_in[6];
    const float* b_se       = (const float*)d_in[7];
    const float* cell_emb   = (const float*)d_in[8];
    const float* W_f1       = (const float*)d_in[9];
    const float* b_f1       = (const float*)d_in[10];
    const float* W_f2       = (const float*)d_in[11];
    const float* b_f2       = (const float*)d_in[12];
    const float* Wself      = (const float*)d_in[13];
    const float* Wrel       = (const float*)d_in[14];
    const float* ln_g       = (const float*)d_in[15];
    const float* ln_b       = (const float*)d_in[16];
    const float* W_out      = (const float*)d_in[17];
    const float* b_out      = (const float*)d_in[18];
    float* out = (float*)d_out;

    char* p = (char*)d_ws;
    auto alloc = [&](size_t bytes)->char*{
        char* r = p; p += (bytes + 255) & ~(size_t)255; return r;
    };
    int*   deg    = (int*)  alloc((size_t)DEGW*4);       /* padded, 1.92MB */
    u32*   epack  = (u32*)  alloc((size_t)Rk*Nk*64*4);   /* ELL 4B, 7.68MB */
    float* hid    = (float*)alloc((size_t)Bk*64*4);
    u16*   xh     = (u16*)  alloc((size_t)Bk*Nk*64*2);
    u16*   aggh   = (u16*)  alloc((size_t)3*Bk*Nk*64*2);
    u16*   wt     = (u16*)  alloc((size_t)Lk*16384*2);

    // prep: weights + padded-deg zero + FiLM-1
    k_prep0<<<256 + Bk*64, 256, 0, stream>>>(Wself, Wrel, wt, deg,
                                             drug_fp, W_f1, b_f1, hid);
    // XCD-partitioned ELL edge fill || x0 init (one dispatch)
    k_efx<<<8*EFB + INITB, 256, 0, stream>>>(edge_index, edge_w, deg, epack,
                                             ctl, dt, cell_idx, W_se, b_se, cell_emb,
                                             hid, W_f2, b_f2, xh);

    // layers
    const int ntile = (Nk + 63)/64;            // 157
    for(int l = 0; l < Lk; ++l){
        k_agg<<<4*7500, 256, 0, stream>>>(xh, deg, epack, aggh);
        k_proj_mfma<<<ntile*8, 256, 0, stream>>>(
            xh, aggh, wt, ln_g, ln_b, l,
            (l == Lk-1) ? 1 : 0, W_out, b_out, out);
    }
}

// Round 11
// 354.602 us; speedup vs baseline: 4.2786x; 1.0043x over previous
//
#include <hip/hip_runtime.h>
#include <hip/hip_bf16.h>
#include <math.h>

#define Bk 8
#define Nk 10000
#define Hk 64
#define Lk 4
#define Rk 3
#define Ek 200000
#define FPk 2048

#define C4 (Rk*Ek/4)              /* 150000 edge-quads */
#define EFB ((C4 + 255)/256)      /* 586 per-XCD edge-scan block groups */
#define INITB 2048                /* 8 batches x 256 x0-init blocks */
#define DEGW  (Rk*Nk*16)          /* padded deg: one counter per 64B line */
#define NPART 1250                /* dst nodes per XCD partition */

typedef unsigned short u16;
typedef unsigned int   u32;
typedef _Float16 f16;
typedef __attribute__((ext_vector_type(2))) _Float16 f16x2;
typedef __attribute__((ext_vector_type(8))) _Float16 f16x8;
typedef __attribute__((ext_vector_type(4))) float f32x4;

__device__ __forceinline__ f16x2 as_h2(u32 u){
    union{u32 i; f16x2 h;} v; v.i = u; return v.h;
}
__device__ __forceinline__ u16 f2h_bits(float f){
    union{f16 h; u16 u;} v; v.h = (f16)f; return v.u;
}

// ---------------------------------------------------------------------------
// k_prep0: weight prep (fp16, MFMA B layout) + padded-deg zeroing
//          (blocks 0..255) + FiLM stage 1 (blocks 256..767).  [R5-proven]
// ---------------------------------------------------------------------------
__global__ void k_prep0(const float* __restrict__ Wself, const float* __restrict__ Wrel,
                        u16* __restrict__ wt, int* __restrict__ deg,
                        const float* __restrict__ fp, const float* __restrict__ W1,
                        const float* __restrict__ b1, float* __restrict__ hid){
    __shared__ float red[256];
    if(blockIdx.x < 256){
        int idx = blockIdx.x*256 + threadIdx.x;      // 0..65535
        if(idx < DEGW/8){                            // zero 8 ints each (60000 thr)
            *(int4*)&deg[idx*8]     = make_int4(0,0,0,0);
            *(int4*)&deg[idx*8 + 4] = make_int4(0,0,0,0);
        }
        int j    = idx & 7;
        int lane = (idx >> 3) & 63;
        int jt   = (idx >> 9) & 3;
        int kc   = (idx >> 11) & 1;
        int mt   = (idx >> 12) & 3;
        int l    = idx >> 14;
        int k    = kc*32 + (lane >> 4)*8 + j;
        int col  = jt*16 + (lane & 15);
        float w = (mt == 0) ? Wself[(l*64 + k)*64 + col]
                            : Wrel[((l*3 + (mt-1))*64 + k)*64 + col];
        wt[idx] = f2h_bits(w);
    }else{
        int bb = blockIdx.x - 256;                   // 0..511
        int b = bb >> 6, h = bb & 63;
        const float* fpb = fp + b*FPk;
        float acc = 0.f;
        for(int k = threadIdx.x; k < FPk; k += 256)
            acc += fpb[k] * W1[k*64 + h];
        red[threadIdx.x] = acc;
        __syncthreads();
        for(int s = 128; s >= 1; s >>= 1){
            if(threadIdx.x < s) red[threadIdx.x] += red[threadIdx.x + s];
            __syncthreads();
        }
        if(threadIdx.x == 0) hid[b*64 + h] = fmaxf(red[0] + b1[h], 0.f);
    }
}

// ---------------------------------------------------------------------------
// k_efx: XCD-partitioned ELL edge fill + x0 init, one dispatch.  [R10-proven]
// x0 now written in batch-pair-interleaved layout x2[b>>1][node][(b&1)*64+f].
// ---------------------------------------------------------------------------
__global__ void k_efx(const int* __restrict__ edge_index, const float* __restrict__ edge_weight,
                      int* __restrict__ deg, u32* __restrict__ epack,
                      const float* __restrict__ ctl, const float* __restrict__ dt,
                      const int* __restrict__ cell_idx,
                      const float* __restrict__ W_se, const float* __restrict__ b_se,
                      const float* __restrict__ cell_emb,
                      const float* __restrict__ hid, const float* __restrict__ W2,
                      const float* __restrict__ b2,
                      u16* __restrict__ x2){
    __shared__ float g1l[64], btl[64];
    if(blockIdx.x < 8*EFB){
        int part = blockIdx.x & 7;                  // XCD partition (dst range)
        int idx  = (blockIdx.x >> 3)*256 + threadIdx.x;
        if(idx >= C4) return;
        int g = idx*4;
        int r = g / Ek, e = g % Ek;                 // Ek%4==0 -> quad shares r
        int4   d4 = *(const int4*)  &edge_index [r*2*Ek + Ek + e];
        int lo = part*NPART, hi = lo + NPART;
        if((d4.x < lo || d4.x >= hi) && (d4.y < lo || d4.y >= hi) &&
           (d4.z < lo || d4.z >= hi) && (d4.w < lo || d4.w >= hi)) return;
        int4   s4 = *(const int4*)  &edge_index [r*2*Ek + e];
        float4 w4 = *(const float4*)&edge_weight[r*Ek + e];
        int* dg = deg + (size_t)r*Nk*16;
        size_t ebase = (size_t)r*Nk;
        int pos;
        if(d4.x >= lo && d4.x < hi){
            pos = atomicAdd(&dg[(size_t)d4.x*16], 1);
            if(pos < 64) epack[((ebase + d4.x) << 6) + pos] = ((u32)f2h_bits(w4.x) << 16) | (u32)s4.x;
        }
        if(d4.y >= lo && d4.y < hi){
            pos = atomicAdd(&dg[(size_t)d4.y*16], 1);
            if(pos < 64) epack[((ebase + d4.y) << 6) + pos] = ((u32)f2h_bits(w4.y) << 16) | (u32)s4.y;
        }
        if(d4.z >= lo && d4.z < hi){
            pos = atomicAdd(&dg[(size_t)d4.z*16], 1);
            if(pos < 64) epack[((ebase + d4.z) << 6) + pos] = ((u32)f2h_bits(w4.z) << 16) | (u32)s4.z;
        }
        if(d4.w >= lo && d4.w < hi){
            pos = atomicAdd(&dg[(size_t)d4.w*16], 1);
            if(pos < 64) epack[((ebase + d4.w) << 6) + pos] = ((u32)f2h_bits(w4.w) << 16) | (u32)s4.w;
        }
    }else{
        int vb  = blockIdx.x - 8*EFB;               // 0..2047
        int b   = vb >> 8;                          // batch
        int blk = vb & 255;
        int t = threadIdx.x;
        if(t < 128){
            float acc = b2[t];
            #pragma unroll 8
            for(int k = 0; k < 64; ++k)
                acc += hid[b*64 + k] * W2[k*128 + t];
            if(t < 64) g1l[t] = 1.f + tanhf(acc);
            else       btl[t - 64] = acc;
        }
        __syncthreads();
        int ci = cell_idx[b];
        size_t xbase = (size_t)(b >> 1)*Nk*128 + (b & 1)*64;   // interleaved
        const int per_b = Nk*8;                     // 80000 feat-octets
        for(int o = blk*256 + t; o < per_b; o += 256*256){
            int hq = o & 7;
            int n  = o >> 3;
            float c = ctl[b*Nk + n], d = dt[b*Nk + n];
            u32 pk[4];
            #pragma unroll
            for(int j = 0; j < 8; j += 2){
                int h0 = hq*8 + j, h1 = h0 + 1;
                float w0 = W_se[h0], s0 = b_se[h0];
                float w1 = W_se[h1], s1 = b_se[h1];
                float v0 = fmaxf(c*w0 + s0, 0.f) + fmaxf(d*w0 + s0, 0.f)
                         + cell_emb[ci*64 + h0];
                float v1 = fmaxf(c*w1 + s1, 0.f) + fmaxf(d*w1 + s1, 0.f)
                         + cell_emb[ci*64 + h1];
                v0 = v0 * g1l[h0] + btl[h0];
                v1 = v1 * g1l[h1] + btl[h1];
                pk[j >> 1] = (u32)f2h_bits(v0) | ((u32)f2h_bits(v1) << 16);
            }
            *(int4*)&x2[xbase + (size_t)n*128 + hq*8] = make_int4(pk[0], pk[1], pk[2], pk[3]);
        }
    }
}

// ---------------------------------------------------------------------------
// agg (fp16): R0-proven hot loop, ELL addressing, NOW with batch-pair-
// interleaved x2: each edge's gather for both batches is ONE contiguous 256B
// segment (was 2 disjoint 128B segments in separate arrays). Line count,
// instruction count, lane mapping (byte off = lane*4) all identical — the
// only changed variable is segment contiguity. Probes whether the L2 random
// floor (12.3 TB/s = 36% of sequential ubench; invariant across R0/R2/R3)
// is per-discontiguous-transaction overhead. Stash offset: src<<8.
// bpair=blockIdx&3 -> per-XCD 2.56MB x2 slice (L2-resident, R8 FETCH-proven).
// ---------------------------------------------------------------------------
__global__ __launch_bounds__(256) void k_agg(const u16* __restrict__ x2,
                      const int* __restrict__ deg, const u32* __restrict__ epack,
                      u16* __restrict__ aggh){
    __shared__ int2 stash[4][64];
    int bpair = blockIdx.x & 3;
    int grp   = blockIdx.x >> 2;                   // 0..7499
    int wq    = threadIdx.x >> 6;
    int wid   = grp*4 + wq;                        // 0..29999 = (r,dst)
    int lane  = threadIdx.x & 63;
    int fg    = lane & 31;                         // feat dword: feats fg*2, fg*2+1
    int bl    = lane >> 5;                         // local batch 0/1
    int b     = bpair*2 + bl;
    int r = wid / Nk, dst = wid % Nk;
    int cnt = deg[(size_t)wid*16]; if(cnt > 64) cnt = 64;
    const u32* ep = epack + ((size_t)wid << 6);
    const char* xb = (const char*)x2 + (size_t)bpair*Nk*256 + lane*4;

    f16x2 A = (f16x2){0,0}, C = (f16x2){0,0};      // 2 accumulation chains
    int2* st = stash[wq];
    if(lane < cnt){
        u32 e = ep[lane];
        st[lane] = make_int2((int)((e & 0xFFFFu) << 8),
                             (int)((e >> 16) | (e & 0xFFFF0000u)));
    }
    int t = 0;
    for(; t + 8 <= cnt; t += 8){
        int4 q01 = *(const int4*)&st[t];
        int4 q23 = *(const int4*)&st[t+2];
        int4 q45 = *(const int4*)&st[t+4];
        int4 q67 = *(const int4*)&st[t+6];
        u32 u0 = *(const u32*)(xb + q01.x);
        u32 u1 = *(const u32*)(xb + q01.z);
        u32 u2 = *(const u32*)(xb + q23.x);
        u32 u3 = *(const u32*)(xb + q23.z);
        u32 u4 = *(const u32*)(xb + q45.x);
        u32 u5 = *(const u32*)(xb + q45.z);
        u32 u6 = *(const u32*)(xb + q67.x);
        u32 u7 = *(const u32*)(xb + q67.z);
        A += as_h2(u0)*as_h2(q01.y); C += as_h2(u1)*as_h2(q01.w);
        A += as_h2(u2)*as_h2(q23.y); C += as_h2(u3)*as_h2(q23.w);
        A += as_h2(u4)*as_h2(q45.y); C += as_h2(u5)*as_h2(q45.w);
        A += as_h2(u6)*as_h2(q67.y); C += as_h2(u7)*as_h2(q67.w);
    }
    for(; t + 2 <= cnt; t += 2){
        int4 q01 = *(const int4*)&st[t];
        u32 u0 = *(const u32*)(xb + q01.x);
        u32 u1 = *(const u32*)(xb + q01.z);
        A += as_h2(u0)*as_h2(q01.y); C += as_h2(u1)*as_h2(q01.w);
    }
    if(t < cnt){
        int2 p = st[t];
        u32 u = *(const u32*)(xb + p.x);
        A += as_h2(u)*as_h2(p.y);
    }
    float a0 = (float)A.x + (float)C.x;
    float a1 = (float)A.y + (float)C.y;
    u32 packed = (u32)f2h_bits(a0) | ((u32)f2h_bits(a1) << 16);
    ((u32*)aggh)[(((size_t)r*Bk + b)*Nk + dst)*32 + fg] = packed;
}

// ---------------------------------------------------------------------------
// MFMA projection (fp16) + LN + ReLU (+ fused readout on last layer).
// wt staged in LDS; 64 nodes/block (16/wave), 1256 blocks.  [R8]
// Self-term / x-write use the interleaved x2 layout (row stride 256B,
// per-batch 128B halves — contiguity of each access unchanged).
// b-map keeps proj XCD == one of agg's two writer XCDs for batch b.
// ---------------------------------------------------------------------------
__global__ __launch_bounds__(256) void k_proj_mfma(u16* __restrict__ x2,
        const u16* __restrict__ aggh, const u16* __restrict__ wt,
        const float* __restrict__ ln_g, const float* __restrict__ ln_b, int l,
        int last, const float* __restrict__ W_out, const float* __restrict__ b_out,
        float* __restrict__ out){
    __shared__ u16 wls[16384];
    const u16* wl = wt + (size_t)l*16384;
    for(int i = threadIdx.x; i < 2048; i += 256)
        *(int4*)&wls[i*8] = *(const int4*)&wl[i*8];
    __syncthreads();

    int lane = threadIdx.x & 63;
    int wq   = threadIdx.x >> 6;
    int k8   = blockIdx.x & 7;
    int b    = ((k8 & 3) << 1) | (k8 >> 2);   // inverse of xcd(b)=(b>>1)+4*(b&1)
    int tile = blockIdx.x >> 3;
    int n0   = tile*64 + wq*16;               // 16 nodes for this wave
    int mrow = lane & 15;
    int kq   = lane >> 4;
    int nA = n0 + mrow; if(nA >= Nk) nA = Nk - 1;

    size_t xbase = (size_t)(b >> 1)*Nk*128 + (b & 1)*64;   // interleaved x2

    f32x4 acc[4];
    #pragma unroll
    for(int jt = 0; jt < 4; ++jt) acc[jt] = (f32x4){0.f,0.f,0.f,0.f};

    #pragma unroll
    for(int mt = 0; mt < 4; ++mt){
        const u16* arowA = (mt == 0)
            ? x2 + xbase + (size_t)nA*128
            : aggh + (((size_t)(mt-1)*Bk + b)*Nk)*64 + (size_t)nA*64;
        #pragma unroll
        for(int kc = 0; kc < 2; ++kc){
            f16x8 aA = *(const f16x8*)(arowA + kc*32 + kq*8);
            #pragma unroll
            for(int jt = 0; jt < 4; ++jt){
                f16x8 bfrag = *(const f16x8*)(wls + ((size_t)((mt*2 + kc)*4 + jt)*64 + lane)*8);
                acc[jt] = __builtin_amdgcn_mfma_f32_16x16x32_f16(aA, bfrag, acc[jt], 0, 0, 0);
            }
        }
    }

    float gv[4], bv[4], wo[4];
    #pragma unroll
    for(int jt = 0; jt < 4; ++jt){
        int f = jt*16 + mrow;
        gv[jt] = ln_g[l*64 + f];
        bv[jt] = ln_b[l*64 + f];
        wo[jt] = W_out[f];
    }
    float bo = b_out[0];
    u16* xdst = x2 + xbase;

    #pragma unroll
    for(int v = 0; v < 4; ++v){
        float s1 = acc[0][v] + acc[1][v] + acc[2][v] + acc[3][v];
        float s2 = acc[0][v]*acc[0][v] + acc[1][v]*acc[1][v]
                 + acc[2][v]*acc[2][v] + acc[3][v]*acc[3][v];
        #pragma unroll
        for(int off = 1; off <= 8; off <<= 1){
            s1 += __shfl_xor(s1, off);
            s2 += __shfl_xor(s2, off);
        }
        float mu  = s1 * 0.015625f;
        float var = s2 * 0.015625f - mu*mu;
        float rstd = rsqrtf(var + 1e-3f);
        int node = n0 + kq*4 + v;
        if(!last){
            if(node < Nk){
                #pragma unroll
                for(int jt = 0; jt < 4; ++jt){
                    float o = (acc[jt][v] - mu) * rstd * gv[jt] + bv[jt];
                    xdst[(size_t)node*128 + jt*16 + mrow] = f2h_bits(fmaxf(o, 0.f));
                }
            }
        }else{
            float s3 = 0.f;
            #pragma unroll
            for(int jt = 0; jt < 4; ++jt){
                float o = (acc[jt][v] - mu) * rstd * gv[jt] + bv[jt];
                s3 += fmaxf(o, 0.f) * wo[jt];
            }
            #pragma unroll
            for(int off = 1; off <= 8; off <<= 1)
                s3 += __shfl_xor(s3, off);
            if(mrow == 0 && node < Nk)
                out[(size_t)b*Nk + node] = s3 + bo;
        }
    }
}

// ---------------------------------------------------------------------------
extern "C" void kernel_launch(void* const* d_in, const int* in_sizes, int n_in,
                              void* d_out, int out_size, void* d_ws, size_t ws_size,
                              hipStream_t stream){
    const float* ctl        = (const float*)d_in[0];
    const float* dt         = (const float*)d_in[1];
    const float* drug_fp    = (const float*)d_in[2];
    const float* edge_w     = (const float*)d_in[3];
    const int*   cell_idx   = (const int*)  d_in[4];
    const int*   edge_index = (const int*)  d_in[5];
    const float* W_se       = (const float*)d_in[6];
    const float* b_se       = (const float*)d_in[7];
    const float* cell_emb   = (const float*)d_in[8];
    const float* W_f1       = (const float*)d_in[9];
    const float* b_f1       = (const float*)d_in[10];
    const float* W_f2       = (const float*)d_in[11];
    const float* b_f2       = (const float*)d_in[12];
    const float* Wself      = (const float*)d_in[13];
    const float* Wrel       = (const float*)d_in[14];
    const float* ln_g       = (const float*)d_in[15];
    const float* ln_b       = (const float*)d_in[16];
    const float* W_out      = (const float*)d_in[17];
    const float* b_out      = (const float*)d_in[18];
    float* out = (float*)d_out;

    char* p = (char*)d_ws;
    auto alloc = [&](size_t bytes)->char*{
        char* r = p; p += (bytes + 255) & ~(size_t)255; return r;
    };
    int*   deg    = (int*)  alloc((size_t)DEGW*4);       /* padded, 1.92MB */
    u32*   epack  = (u32*)  alloc((size_t)Rk*Nk*64*4);   /* ELL 4B, 7.68MB */
    float* hid    = (float*)alloc((size_t)Bk*64*4);
    u16*   x2     = (u16*)  alloc((size_t)Bk*Nk*64*2);   /* interleaved pairs */
    u16*   aggh   = (u16*)  alloc((size_t)3*Bk*Nk*64*2);
    u16*   wt     = (u16*)  alloc((size_t)Lk*16384*2);

    // prep: weights + padded-deg zero + FiLM-1
    k_prep0<<<256 + Bk*64, 256, 0, stream>>>(Wself, Wrel, wt, deg,
                                             drug_fp, W_f1, b_f1, hid);
    // XCD-partitioned ELL edge fill || x0 init (one dispatch)
    k_efx<<<8*EFB + INITB, 256, 0, stream>>>(edge_index, edge_w, deg, epack,
                                             ctl, dt, cell_idx, W_se, b_se, cell_emb,
                                             hid, W_f2, b_f2, x2);

    // layers
    const int ntile = (Nk + 63)/64;            // 157
    for(int l = 0; l < Lk; ++l){
        k_agg<<<4*7500, 256, 0, stream>>>(x2, deg, epack, aggh);
        k_proj_mfma<<<ntile*8, 256, 0, stream>>>(
            x2, aggh, wt, ln_g, ln_b, l,
            (l == Lk-1) ? 1 : 0, W_out, b_out, out);
    }
}